// Round 2
// baseline (623.871 us; speedup 1.0000x reference)
//
#include <hip/hip_runtime.h>
#include <hip/hip_bf16.h>
#include <cstdint>
#include <cstddef>

#define S_ 256
#define N_ 1024
#define H_ 512
#define AD_ 128

typedef __attribute__((ext_vector_type(8))) short short8;
typedef __attribute__((ext_vector_type(4))) float f32x4;

// pack 8 f32 -> 8 bf16 (RNE; compiler emits v_cvt_pk_bf16_f32)
__device__ __forceinline__ short8 pack8(float4 a, float4 b) {
  union { short8 s; __hip_bfloat162 h[4]; } u;
  u.h[0] = __float22bfloat162_rn(make_float2(a.x, a.y));
  u.h[1] = __float22bfloat162_rn(make_float2(a.z, a.w));
  u.h[2] = __float22bfloat162_rn(make_float2(b.x, b.y));
  u.h[3] = __float22bfloat162_rn(make_float2(b.z, b.w));
  return u.s;
}

// ---------------------------------------------------------------------------
// K0: W1 [H][AD] f32 -> MFMA-fragment-ordered bf16:
//   w1f[st*65536 + kk*4096 + c*512 + lane*8 + j] = bf16(W1[kk*32+(lane>>4)*8+j][c*16+(lane&15)])
// so a wave's B-fragment load is a linear 16B/lane global load.
// ---------------------------------------------------------------------------
__global__ __launch_bounds__(256) void k_w1frag(
    const float* __restrict__ w1_pre, const float* __restrict__ w1_fol,
    unsigned short* __restrict__ w1f) {
  int idx = blockIdx.x * 256 + threadIdx.x;  // 0..65535
  int st = blockIdx.y;
  const float* w1 = st ? w1_fol : w1_pre;
  int j = idx & 7;
  int lane = (idx >> 3) & 63;
  int c = (idx >> 9) & 7;
  int kk = idx >> 12;
  int k = kk * 32 + ((lane >> 4) << 3) + j;
  int d = c * 16 + (lane & 15);
  __hip_bfloat16 hb = __float2bfloat16(w1[(size_t)k * AD_ + d]);
  w1f[(size_t)st * 65536 + idx] = *(unsigned short*)&hb;
}

// ---------------------------------------------------------------------------
// K1: inclusive prefix sum of is_valid -> pos (rank-1), per stream.
// ---------------------------------------------------------------------------
__global__ __launch_bounds__(1024) void k_scan(
    const int* __restrict__ valid_pre, const int* __restrict__ valid_fol,
    int* __restrict__ pos) {
  const int st = blockIdx.x;
  const int* valid = st ? valid_fol : valid_pre;
  __shared__ int buf[1024];
  const int t = threadIdx.x;
  buf[t] = valid[t];
  __syncthreads();
  for (int off = 1; off < 1024; off <<= 1) {
    int v = (t >= off) ? buf[t - off] : 0;
    __syncthreads();
    buf[t] += v;
    __syncthreads();
  }
  pos[st * N_ + t] = buf[t] - 1;
}

// ---------------------------------------------------------------------------
// blockRed over 8 waves (512 threads)
// ---------------------------------------------------------------------------
template <bool MAXRED>
__device__ __forceinline__ float blockRed(float v, float* buf) {
#pragma unroll
  for (int off = 32; off; off >>= 1) {
    float o = __shfl_xor(v, off);
    v = MAXRED ? fmaxf(v, o) : (v + o);
  }
  __syncthreads();
  if ((threadIdx.x & 63) == 0) buf[threadIdx.x >> 6] = v;
  __syncthreads();
  float r = buf[0];
#pragma unroll
  for (int i = 1; i < 8; ++i) r = MAXRED ? fmaxf(r, buf[i]) : (r + buf[i]);
  return r;
}

// ---------------------------------------------------------------------------
// K2: fused per-(n,stream): logits (MFMA, no LDS) -> double softmax -> PV.
// 512 threads = 8 waves; wave w owns s-rows [w*32, w*32+32).
// ---------------------------------------------------------------------------
__global__ __launch_bounds__(512, 2) void k_fused(
    const float* __restrict__ emb_pre, const float* __restrict__ emb_fol,
    const unsigned short* __restrict__ w1f,
    const float* __restrict__ w2_pre, const float* __restrict__ w2_fol,
    const unsigned char* __restrict__ mask_pre, const unsigned char* __restrict__ mask_fol,
    const int* __restrict__ valid_pre, const int* __restrict__ valid_fol,
    const int* __restrict__ pos,
    float* __restrict__ out) {
  __shared__ float lg[S_][2];
  __shared__ float wl[S_];
  __shared__ float redbuf[8];
  __shared__ __align__(16) float part[4][128][4];

  const int t = threadIdx.x;
  const int w = t >> 6, lane = t & 63;
  const int r16 = lane & 15, kq = lane >> 4;

  for (int pair = blockIdx.x; pair < 2 * N_; pair += gridDim.x) {
    const int st = pair & 1, n = pair >> 1;
    const float* __restrict__ emb = st ? emb_fol : emb_pre;
    const float* __restrict__ w2  = st ? w2_fol : w2_pre;
    const unsigned char* __restrict__ mask = st ? mask_fol : mask_pre;
    const int* __restrict__ valid = st ? valid_fol : valid_pre;

    if (valid[n] <= 0) {  // uniform per block
      if (t < 128) {
        float4 z = {0.f, 0.f, 0.f, 0.f};
        *(float4*)&out[(size_t)n * 1024 + st * 512 + t * 4] = z;
      }
      continue;
    }
    const int np = pos[st * N_ + n];

    // ---------------- phase 1: logits via MFMA, A from global, B from w1f
    f32x4 acc[2][8];
#pragma unroll
    for (int f = 0; f < 2; ++f)
#pragma unroll
      for (int c = 0; c < 8; ++c) acc[f][c] = (f32x4){0.f, 0.f, 0.f, 0.f};

    const float* a0 = emb + ((size_t)(w * 32 + r16) * N_ + np) * H_ + kq * 8;
    const unsigned short* bb = w1f + (size_t)st * 65536 + lane * 8;

#pragma unroll 2
    for (int kk = 0; kk < 16; ++kk) {
      short8 b[8];
#pragma unroll
      for (int c = 0; c < 8; ++c)
        b[c] = *(const short8*)(bb + kk * 4096 + c * 512);
#pragma unroll
      for (int f = 0; f < 2; ++f) {
        const float* ap = a0 + (size_t)f * 16 * N_ * H_ + kk * 32;
        float4 x0 = *(const float4*)ap;
        float4 x1 = *(const float4*)(ap + 4);
        short8 a = pack8(x0, x1);
#pragma unroll
        for (int c = 0; c < 8; ++c)
          acc[f][c] = __builtin_amdgcn_mfma_f32_16x16x32_bf16(a, b[c], acc[f][c], 0, 0, 0);
      }
    }

    // epilogue: tanh then @W2, reduce over the 16 col-lanes
    float w2v[8][2];
#pragma unroll
    for (int c = 0; c < 8; ++c) {
      w2v[c][0] = w2[(c * 16 + r16) * 2 + 0];
      w2v[c][1] = w2[(c * 16 + r16) * 2 + 1];
    }
#pragma unroll
    for (int f = 0; f < 2; ++f) {
#pragma unroll
      for (int q = 0; q < 4; ++q) {
        float p0 = 0.f, p1 = 0.f;
#pragma unroll
        for (int c = 0; c < 8; ++c) {
          float th = tanhf(acc[f][c][q]);
          p0 += th * w2v[c][0];
          p1 += th * w2v[c][1];
        }
        p0 += __shfl_xor(p0, 1); p0 += __shfl_xor(p0, 2);
        p0 += __shfl_xor(p0, 4); p0 += __shfl_xor(p0, 8);
        p1 += __shfl_xor(p1, 1); p1 += __shfl_xor(p1, 2);
        p1 += __shfl_xor(p1, 4); p1 += __shfl_xor(p1, 8);
        if (r16 == 0) {
          int row = w * 32 + f * 16 + kq * 4 + q;
          lg[row][0] = p0;
          lg[row][1] = p1;
        }
      }
    }
    __syncthreads();

    // ---------------- phase 2: double softmax over s, fold mean over r
    const bool act = (t < S_);
    float lv[2] = {-INFINITY, -INFINITY};
    bool mk = false;
    if (act) {
      lv[0] = lg[t][0];
      lv[1] = lg[t][1];
      mk = mask[(size_t)np * S_ + t] != 0;
    }
    float qv[2];
#pragma unroll
    for (int r = 0; r < 2; ++r) {
      float m1 = blockRed<true>(lv[r], redbuf);
      float e1 = act ? __expf(lv[r] - m1) : 0.f;
      float s1 = blockRed<false>(e1, redbuf);
      float p1 = e1 / s1;                        // first softmax
      float v  = (act && !mk) ? p1 : -INFINITY;  // mask probabilities
      float m2 = blockRed<true>(v, redbuf);
      float e2 = (act && !mk) ? __expf(v - m2) : 0.f;
      float s2 = blockRed<false>(e2, redbuf);
      qv[r] = e2 / s2;                           // second softmax
    }
    if (act) wl[t] = 0.5f * (qv[0] + qv[1]);
    __syncthreads();

    // ---------------- phase 3: PV, f32 re-read (L3-resident tile)
    const int sg = t >> 7, hh = (t & 127) * 4;
    float ax = 0.f, ay = 0.f, az = 0.f, aw = 0.f;
#pragma unroll 4
    for (int s = sg; s < S_; s += 4) {
      float4 x = *(const float4*)(emb + ((size_t)s * N_ + np) * H_ + hh);
      float ww = wl[s];
      ax += ww * x.x;
      ay += ww * x.y;
      az += ww * x.z;
      aw += ww * x.w;
    }
    part[sg][t & 127][0] = ax;
    part[sg][t & 127][1] = ay;
    part[sg][t & 127][2] = az;
    part[sg][t & 127][3] = aw;
    __syncthreads();
    if (t < 128) {
      float4 r;
      r.x = part[0][t][0] + part[1][t][0] + part[2][t][0] + part[3][t][0];
      r.y = part[0][t][1] + part[1][t][1] + part[2][t][1] + part[3][t][1];
      r.z = part[0][t][2] + part[1][t][2] + part[2][t][2] + part[3][t][2];
      r.w = part[0][t][3] + part[1][t][3] + part[2][t][3] + part[3][t][3];
      *(float4*)&out[(size_t)n * 1024 + st * 512 + t * 4] = r;
    }
    __syncthreads();
  }
}

// ---------------------------------------------------------------------------
extern "C" void kernel_launch(void* const* d_in, const int* in_sizes, int n_in,
                              void* d_out, int out_size, void* d_ws, size_t ws_size,
                              hipStream_t stream) {
  const float* emb_pre = (const float*)d_in[0];
  const float* emb_fol = (const float*)d_in[1];
  const unsigned char* mask_pre = (const unsigned char*)d_in[2];
  const unsigned char* mask_fol = (const unsigned char*)d_in[3];
  const int* valid_pre = (const int*)d_in[4];
  const int* valid_fol = (const int*)d_in[5];
  const float* w1_pre = (const float*)d_in[6];
  const float* w2_pre = (const float*)d_in[7];
  const float* w1_fol = (const float*)d_in[8];
  const float* w2_fol = (const float*)d_in[9];
  float* out = (float*)d_out;

  char* ws = (char*)d_ws;
  unsigned short* w1f = (unsigned short*)ws;          // 256 KiB
  int* pos = (int*)(ws + 262144);                     // 8 KiB

  hipLaunchKernelGGL(k_w1frag, dim3(256, 2), dim3(256), 0, stream,
                     w1_pre, w1_fol, w1f);
  hipLaunchKernelGGL(k_scan, dim3(2), dim3(1024), 0, stream,
                     valid_pre, valid_fol, pos);
  hipLaunchKernelGGL(k_fused, dim3(256), dim3(512), 0, stream,
                     emb_pre, emb_fol, w1f, w2_pre, w2_fol,
                     mask_pre, mask_fol, valid_pre, valid_fol, pos, out);
}

// Round 3
// 592.269 us; speedup vs baseline: 1.0534x; 1.0534x over previous
//
#include <hip/hip_runtime.h>
#include <hip/hip_bf16.h>
#include <cstdint>
#include <cstddef>

#define S_ 256
#define N_ 1024
#define H_ 512
#define AD_ 128

typedef __attribute__((ext_vector_type(8))) short short8;
typedef __attribute__((ext_vector_type(4))) float f32x4;

// pack 8 f32 -> 8 bf16 (RNE)
__device__ __forceinline__ short8 pack8(float4 a, float4 b) {
  union { short8 s; __hip_bfloat162 h[4]; } u;
  u.h[0] = __float22bfloat162_rn(make_float2(a.x, a.y));
  u.h[1] = __float22bfloat162_rn(make_float2(a.z, a.w));
  u.h[2] = __float22bfloat162_rn(make_float2(b.x, b.y));
  u.h[3] = __float22bfloat162_rn(make_float2(b.z, b.w));
  return u.s;
}

// ---------------------------------------------------------------------------
// K0: W1 [H][AD] f32 -> MFMA-fragment-ordered bf16 (B-frag = linear 16B/lane).
// ---------------------------------------------------------------------------
__global__ __launch_bounds__(256) void k_w1frag(
    const float* __restrict__ w1_pre, const float* __restrict__ w1_fol,
    unsigned short* __restrict__ w1f) {
  int idx = blockIdx.x * 256 + threadIdx.x;  // 0..65535
  int st = blockIdx.y;
  const float* w1 = st ? w1_fol : w1_pre;
  int j = idx & 7;
  int lane = (idx >> 3) & 63;
  int c = (idx >> 9) & 7;
  int kk = idx >> 12;
  int k = kk * 32 + ((lane >> 4) << 3) + j;
  int d = c * 16 + (lane & 15);
  __hip_bfloat16 hb = __float2bfloat16(w1[(size_t)k * AD_ + d]);
  w1f[(size_t)st * 65536 + idx] = *(unsigned short*)&hb;
}

// ---------------------------------------------------------------------------
// K1: inclusive prefix sum of is_valid -> pos (rank-1), per stream.
// ---------------------------------------------------------------------------
__global__ __launch_bounds__(1024) void k_scan(
    const int* __restrict__ valid_pre, const int* __restrict__ valid_fol,
    int* __restrict__ pos) {
  const int st = blockIdx.x;
  const int* valid = st ? valid_fol : valid_pre;
  __shared__ int buf[1024];
  const int t = threadIdx.x;
  buf[t] = valid[t];
  __syncthreads();
  for (int off = 1; off < 1024; off <<= 1) {
    int v = (t >= off) ? buf[t - off] : 0;
    __syncthreads();
    buf[t] += v;
    __syncthreads();
  }
  pos[st * N_ + t] = buf[t] - 1;
}

// ---------------------------------------------------------------------------
// K2: fused per-(n,stream), 1024 threads = 16 waves, wave w owns s-rows
// [w*16, w*16+16). logits (MFMA, no LDS staging) -> 1-wave softmax -> PV (L3).
// ---------------------------------------------------------------------------
__global__ __launch_bounds__(1024, 4) void k_fused(
    const float* __restrict__ emb_pre, const float* __restrict__ emb_fol,
    const unsigned short* __restrict__ w1f,
    const float* __restrict__ w2_pre, const float* __restrict__ w2_fol,
    const unsigned char* __restrict__ mask_pre, const unsigned char* __restrict__ mask_fol,
    const int* __restrict__ valid_pre, const int* __restrict__ valid_fol,
    const int* __restrict__ pos,
    float* __restrict__ out) {
  __shared__ float lg[S_][2];
  __shared__ float wl[S_];
  __shared__ __align__(16) float part[8][128][4];

  const int t = threadIdx.x;
  const int w = t >> 6, lane = t & 63;
  const int r16 = lane & 15, kq = lane >> 4;

  for (int pair = blockIdx.x; pair < 2 * N_; pair += gridDim.x) {
    const int st = pair & 1, n = pair >> 1;
    const float* __restrict__ emb = st ? emb_fol : emb_pre;
    const float* __restrict__ w2  = st ? w2_fol : w2_pre;
    const unsigned char* __restrict__ mask = st ? mask_fol : mask_pre;
    const int* __restrict__ valid = st ? valid_fol : valid_pre;

    if (valid[n] <= 0) {  // uniform per block
      if (t < 128) {
        float4 z = {0.f, 0.f, 0.f, 0.f};
        *(float4*)&out[(size_t)n * 1024 + st * 512 + t * 4] = z;
      }
      continue;
    }
    const int np = pos[st * N_ + n];

    // early mask prefetch (wave 0 handles softmax; s = lane*4 + i)
    uchar4 mkb = {0, 0, 0, 0};
    if (w == 0) mkb = *(const uchar4*)(mask + (size_t)np * S_ + lane * 4);

    // ---------------- phase 1: logits via MFMA, A global->reg, B from w1f
    f32x4 acc[8];
#pragma unroll
    for (int c = 0; c < 8; ++c) acc[c] = (f32x4){0.f, 0.f, 0.f, 0.f};

    const float* a0 = emb + ((size_t)(w * 16 + r16) * N_ + np) * H_ + kq * 8;
    const unsigned short* bb = w1f + (size_t)st * 65536 + (size_t)lane * 8;

    float4 x0 = *(const float4*)a0;
    float4 x1 = *(const float4*)(a0 + 4);
#pragma unroll 2
    for (int kk = 0; kk < 16; ++kk) {
      float4 y0, y1;
      if (kk < 15) {  // prefetch next A chunk while MFMAs run
        const float* ap = a0 + (kk + 1) * 32;
        y0 = *(const float4*)ap;
        y1 = *(const float4*)(ap + 4);
      }
      short8 a = pack8(x0, x1);
      const unsigned short* bp = bb + kk * 4096;
#pragma unroll
      for (int c = 0; c < 8; ++c) {
        short8 b = *(const short8*)(bp + c * 512);
        acc[c] = __builtin_amdgcn_mfma_f32_16x16x32_bf16(a, b, acc[c], 0, 0, 0);
      }
      if (kk < 15) { x0 = y0; x1 = y1; }
    }

    // epilogue: tanh then @W2, reduce over the 16 col-lanes of each kq group
    float w2v0[8], w2v1[8];
#pragma unroll
    for (int c = 0; c < 8; ++c) {
      w2v0[c] = w2[(c * 16 + r16) * 2 + 0];
      w2v1[c] = w2[(c * 16 + r16) * 2 + 1];
    }
#pragma unroll
    for (int q = 0; q < 4; ++q) {
      float p0 = 0.f, p1 = 0.f;
#pragma unroll
      for (int c = 0; c < 8; ++c) {
        float th = tanhf(acc[c][q]);
        p0 += th * w2v0[c];
        p1 += th * w2v1[c];
      }
      p0 += __shfl_xor(p0, 1); p0 += __shfl_xor(p0, 2);
      p0 += __shfl_xor(p0, 4); p0 += __shfl_xor(p0, 8);
      p1 += __shfl_xor(p1, 1); p1 += __shfl_xor(p1, 2);
      p1 += __shfl_xor(p1, 4); p1 += __shfl_xor(p1, 8);
      if (r16 == 0) {
        int row = w * 16 + kq * 4 + q;
        lg[row][0] = p0;
        lg[row][1] = p1;
      }
    }
    __syncthreads();  // [C] lg ready

    // ---------------- phase 2: double softmax, wave 0 only, pure shfl
    if (w == 0) {
      float l0[4], l1[4];
      bool mk[4];
#pragma unroll
      for (int i = 0; i < 4; ++i) {
        l0[i] = lg[lane * 4 + i][0];
        l1[i] = lg[lane * 4 + i][1];
      }
      mk[0] = mkb.x != 0; mk[1] = mkb.y != 0; mk[2] = mkb.z != 0; mk[3] = mkb.w != 0;

      float q0[4], q1[4];
#pragma unroll
      for (int r = 0; r < 2; ++r) {
        float* lv = r ? l1 : l0;
        float* qq = r ? q1 : q0;
        float m1 = fmaxf(fmaxf(lv[0], lv[1]), fmaxf(lv[2], lv[3]));
#pragma unroll
        for (int off = 32; off; off >>= 1) m1 = fmaxf(m1, __shfl_xor(m1, off));
        float e[4], s1 = 0.f;
#pragma unroll
        for (int i = 0; i < 4; ++i) { e[i] = __expf(lv[i] - m1); s1 += e[i]; }
#pragma unroll
        for (int off = 32; off; off >>= 1) s1 += __shfl_xor(s1, off);
        float inv1 = 1.f / s1;
        float v[4];
#pragma unroll
        for (int i = 0; i < 4; ++i) v[i] = mk[i] ? -INFINITY : e[i] * inv1;
        float m2 = fmaxf(fmaxf(v[0], v[1]), fmaxf(v[2], v[3]));
#pragma unroll
        for (int off = 32; off; off >>= 1) m2 = fmaxf(m2, __shfl_xor(m2, off));
        float e2[4], s2 = 0.f;
#pragma unroll
        for (int i = 0; i < 4; ++i) {
          e2[i] = mk[i] ? 0.f : __expf(v[i] - m2);
          s2 += e2[i];
        }
#pragma unroll
        for (int off = 32; off; off >>= 1) s2 += __shfl_xor(s2, off);
        float inv2 = 1.f / s2;
#pragma unroll
        for (int i = 0; i < 4; ++i) qq[i] = e2[i] * inv2;
      }
      float4 wv;
      wv.x = 0.5f * (q0[0] + q1[0]);
      wv.y = 0.5f * (q0[1] + q1[1]);
      wv.z = 0.5f * (q0[2] + q1[2]);
      wv.w = 0.5f * (q0[3] + q1[3]);
      *(float4*)&wl[lane * 4] = wv;
    }
    __syncthreads();  // [D] wl ready

    // ---------------- phase 3: PV, f32 re-read (L3-resident tile)
    const int sg = t >> 7, hh = (t & 127) * 4;
    float ax = 0.f, ay = 0.f, az = 0.f, aw = 0.f;
#pragma unroll 4
    for (int s = sg; s < S_; s += 8) {
      float4 x = *(const float4*)(emb + ((size_t)s * N_ + np) * H_ + hh);
      float ww = wl[s];
      ax += ww * x.x;
      ay += ww * x.y;
      az += ww * x.z;
      aw += ww * x.w;
    }
    part[sg][t & 127][0] = ax;
    part[sg][t & 127][1] = ay;
    part[sg][t & 127][2] = az;
    part[sg][t & 127][3] = aw;
    __syncthreads();  // [A] partials ready
    if (t < 128) {
      float4 r = {0.f, 0.f, 0.f, 0.f};
#pragma unroll
      for (int g = 0; g < 8; ++g) {
        r.x += part[g][t][0];
        r.y += part[g][t][1];
        r.z += part[g][t][2];
        r.w += part[g][t][3];
      }
      *(float4*)&out[(size_t)n * 1024 + st * 512 + t * 4] = r;
    }
    __syncthreads();  // [B] part consumed before next pair overwrites
  }
}

// ---------------------------------------------------------------------------
extern "C" void kernel_launch(void* const* d_in, const int* in_sizes, int n_in,
                              void* d_out, int out_size, void* d_ws, size_t ws_size,
                              hipStream_t stream) {
  const float* emb_pre = (const float*)d_in[0];
  const float* emb_fol = (const float*)d_in[1];
  const unsigned char* mask_pre = (const unsigned char*)d_in[2];
  const unsigned char* mask_fol = (const unsigned char*)d_in[3];
  const int* valid_pre = (const int*)d_in[4];
  const int* valid_fol = (const int*)d_in[5];
  const float* w1_pre = (const float*)d_in[6];
  const float* w2_pre = (const float*)d_in[7];
  const float* w1_fol = (const float*)d_in[8];
  const float* w2_fol = (const float*)d_in[9];
  float* out = (float*)d_out;

  char* ws = (char*)d_ws;
  unsigned short* w1f = (unsigned short*)ws;          // 256 KiB
  int* pos = (int*)(ws + 262144);                     // 8 KiB

  hipLaunchKernelGGL(k_w1frag, dim3(256, 2), dim3(256), 0, stream,
                     w1_pre, w1_fol, w1f);
  hipLaunchKernelGGL(k_scan, dim3(2), dim3(1024), 0, stream,
                     valid_pre, valid_fol, pos);
  hipLaunchKernelGGL(k_fused, dim3(256), dim3(1024), 0, stream,
                     emb_pre, emb_fol, w1f, w2_pre, w2_fol,
                     mask_pre, mask_fol, valid_pre, valid_fol, pos, out);
}